// Round 1
// baseline (353.964 us; speedup 1.0000x reference)
//
#include <hip/hip_runtime.h>
#include <math.h>

#define NB 1024   // batch
#define NC 64     // input dim
#define NH 128    // hidden dim
#define MAX_IT 500
#define TOLF 1e-3f

// Weights live in LDS, TRANSPOSED with odd stride 129 so that both the
// streaming (forward matvec, lanes index the output dim) and the row
// (adjoint matvec, lanes index the reduced-into dim) access patterns are
// bank-conflict free:  stream: bank=(k+l)%32 (2 lanes/bank, free);
//                      row:    bank=(c+j)%32 (2 lanes/bank, free).
__launch_bounds__(256, 1)
__global__ void blnn_kernel(const float* __restrict__ xin,
                            const float* __restrict__ Wy0,
                            const float* __restrict__ by0,
                            const float* __restrict__ Wy1,
                            const float* __restrict__ by1,
                            const float* __restrict__ Wz1,
                            const float* __restrict__ Wy2,
                            const float* __restrict__ by2,
                            const float* __restrict__ Wz2,
                            float* __restrict__ out)
{
    __shared__ float Wy0s[NC * 129];   // Wy0s[k*129 + r] = Wy0[r][k]   (64 x 128)
    __shared__ float Wy1s[NC * 129];   // same layout
    __shared__ float Wz1s[NH * 129];   // Wz1s[k*129 + r] = clip(Wz1[r][k]) (128 x 128)
    __shared__ float xbuf [4][NC];
    __shared__ float h0buf[4][NH];
    __shared__ float v1buf[4][NH];
    __shared__ float v0buf[4][NH];
    __shared__ int   flags[4];

    const int tid = threadIdx.x;
    const int s   = tid >> 6;       // wave index = sample-in-block
    const int l   = tid & 63;       // lane
    const int sample = blockIdx.x * 4 + s;

    // ---- stage weights into LDS (transpose + clip), coalesced global reads ----
    for (int idx = tid; idx < NH * NC; idx += 256) {
        const int r = idx >> 6, k = idx & 63;       // Wy* are (H=128, C=64) row-major
        Wy0s[k * 129 + r] = Wy0[idx];
        Wy1s[k * 129 + r] = Wy1[idx];
    }
    for (int idx = tid; idx < NH * NH; idx += 256) {
        const int r = idx >> 7, k = idx & 127;      // Wz1 is (128,128) row-major
        Wz1s[k * 129 + r] = fminf(fmaxf(Wz1[idx], 0.0f), 1e10f);
    }
    // per-lane constants (lane l owns component l of its sample, plus rows l, l+64)
    const float wy2  = Wy2[l];
    const float wz2a = fminf(fmaxf(Wz2[l],      0.0f), 1e10f);
    const float wz2b = fminf(fmaxf(Wz2[l + 64], 0.0f), 1e10f);
    const float b0a = by0[l], b0b = by0[l + 64];
    const float b1a = by1[l], b1b = by1[l + 64];
    const float b2  = by2[0];
    const float z   = xin[sample * NC + l];

    float x1 = 1.0f;          // x1_0 = ones_like(z)
    bool frozen = false;
    __syncthreads();

    for (int it = 0; it < MAX_IT; ++it) {
        if (!frozen) xbuf[s][l] = x1;
        __syncthreads();

        float sig0a = 0.f, sig0b = 0.f, sig2 = 0.f;

        // ---- layer 0 forward: s0 = Wy0 x + by0 ----
        if (!frozen) {
            float a0 = b0a, a1 = b0b;
            #pragma unroll
            for (int k = 0; k < NC; ++k) {
                const float xk = xbuf[s][k];
                a0 = fmaf(Wy0s[k * 129 + l],      xk, a0);
                a1 = fmaf(Wy0s[k * 129 + l + 64], xk, a1);
            }
            sig0a = 1.0f / (1.0f + expf(-a0));
            sig0b = 1.0f / (1.0f + expf(-a1));
            h0buf[s][l]      = fmaxf(a0, 0.0f) + log1pf(expf(-fabsf(a0)));
            h0buf[s][l + 64] = fmaxf(a1, 0.0f) + log1pf(expf(-fabsf(a1)));
        }
        __syncthreads();

        // ---- layer 1 forward + scalar head + v1 ----
        if (!frozen) {
            float a0 = b1a, a1 = b1b;
            #pragma unroll 8
            for (int k = 0; k < NH; ++k) {
                const float hk = h0buf[s][k];
                a0 = fmaf(Wz1s[k * 129 + l],      hk, a0);
                a1 = fmaf(Wz1s[k * 129 + l + 64], hk, a1);
            }
            #pragma unroll
            for (int k = 0; k < NC; ++k) {
                const float xk = xbuf[s][k];
                a0 = fmaf(Wy1s[k * 129 + l],      xk, a0);
                a1 = fmaf(Wy1s[k * 129 + l + 64], xk, a1);
            }
            const float sig1a = 1.0f / (1.0f + expf(-a0));
            const float sig1b = 1.0f / (1.0f + expf(-a1));
            const float h1a = fmaxf(a0, 0.0f) + log1pf(expf(-fabsf(a0)));
            const float h1b = fmaxf(a1, 0.0f) + log1pf(expf(-fabsf(a1)));
            // s2 = Wz2.h1 + Wy2.x + by2  (wave butterfly reduction)
            float p = wz2a * h1a + wz2b * h1b + wy2 * x1;
            #pragma unroll
            for (int off = 32; off > 0; off >>= 1) p += __shfl_xor(p, off, 64);
            sig2 = 1.0f / (1.0f + expf(-(p + b2)));
            v1buf[s][l]      = sig2 * sig1a * wz2a;
            v1buf[s][l + 64] = sig2 * sig1b * wz2b;
        }
        __syncthreads();

        // ---- adjoint: v0 = sig0 * (Wz1^T v1) ----
        if (!frozen) {
            float t0 = 0.f, t1 = 0.f;
            #pragma unroll 8
            for (int j = 0; j < NH; ++j) {
                const float vj = v1buf[s][j];
                t0 = fmaf(Wz1s[l * 129 + j],        vj, t0);
                t1 = fmaf(Wz1s[(l + 64) * 129 + j], vj, t1);
            }
            v0buf[s][l]      = sig0a * t0;
            v0buf[s][l + 64] = sig0b * t1;
        }
        __syncthreads();

        // ---- g = x + sig2*Wy2^T + Wy1^T v1 + Wy0^T v0 ; update + freeze ----
        if (!frozen) {
            float g = fmaf(sig2, wy2, x1);
            #pragma unroll 8
            for (int j = 0; j < NH; ++j)
                g = fmaf(Wy1s[l * 129 + j], v1buf[s][j], g);
            #pragma unroll 8
            for (int j = 0; j < NH; ++j)
                g = fmaf(Wy0s[l * 129 + j], v0buf[s][j], g);
            const float resid = z - g;
            // update happens even on the iteration where convergence triggers
            x1 = fmaf(2.0f / (float)(it + 1), resid, x1);
            float n2 = resid * resid;
            #pragma unroll
            for (int off = 32; off > 0; off >>= 1) n2 += __shfl_xor(n2, off, 64);
            if (sqrtf(n2) < TOLF) frozen = true;   // freezes from NEXT iteration
        }

        if (l == 0) flags[s] = frozen ? 1 : 0;
        __syncthreads();
        if ((flags[0] & flags[1] & flags[2] & flags[3]) != 0) break;
    }

    // output = x1 + CONVEX * z
    out[sample * NC + l] = x1 + z;
}

extern "C" void kernel_launch(void* const* d_in, const int* in_sizes, int n_in,
                              void* d_out, int out_size, void* d_ws, size_t ws_size,
                              hipStream_t stream) {
    const float* xin = (const float*)d_in[0];
    const float* Wy0 = (const float*)d_in[1];
    const float* by0 = (const float*)d_in[2];
    const float* Wy1 = (const float*)d_in[3];
    const float* by1 = (const float*)d_in[4];
    const float* Wz1 = (const float*)d_in[5];
    const float* Wy2 = (const float*)d_in[6];
    const float* by2 = (const float*)d_in[7];
    const float* Wz2 = (const float*)d_in[8];
    float* out = (float*)d_out;

    blnn_kernel<<<dim3(NB / 4), dim3(256), 0, stream>>>(
        xin, Wy0, by0, Wy1, by1, Wz1, Wy2, by2, Wz2, out);
}

// Round 2
// 126.576 us; speedup vs baseline: 2.7965x; 2.7965x over previous
//
#include <hip/hip_runtime.h>
#include <math.h>

#define NB 1024   // batch
#define NC 64     // input dim
#define NH 128    // hidden dim
#define MAX_IT 500
#define TOLF 1e-3f

// Weights live in LDS, TRANSPOSED with odd stride 129 so that both the
// streaming (forward matvec, lanes index the output dim) and the row
// (adjoint matvec, lanes index the reduced-into dim) access patterns are
// bank-conflict free (2 lanes/bank, free on gfx950).
//
// Solver: the reference's Halpern step 2/(i+1) is only O(1/i). Since
// g(x)=x+grad(phi) is 1-strongly monotone, any x with ||g(x)-z||<TOL is
// within TOL of the unique fixed point, so the PATH is free. We use
// per-sample adaptive Richardson: x += lam*(z-g(x)), lam halves on
// residual non-decrease, floored by a Halpern-style 1/(it+2) schedule.
__launch_bounds__(256, 1)
__global__ void blnn_kernel(const float* __restrict__ xin,
                            const float* __restrict__ Wy0,
                            const float* __restrict__ by0,
                            const float* __restrict__ Wy1,
                            const float* __restrict__ by1,
                            const float* __restrict__ Wz1,
                            const float* __restrict__ Wy2,
                            const float* __restrict__ by2,
                            const float* __restrict__ Wz2,
                            float* __restrict__ out)
{
    __shared__ float Wy0s[NC * 129];   // Wy0s[k*129 + r] = Wy0[r][k]   (64 x 128)
    __shared__ float Wy1s[NC * 129];   // same layout
    __shared__ float Wz1s[NH * 129];   // Wz1s[k*129 + r] = clip(Wz1[r][k]) (128 x 128)
    __shared__ float xbuf [4][NC];
    __shared__ float h0buf[4][NH];
    __shared__ float v1buf[4][NH];
    __shared__ float v0buf[4][NH];
    __shared__ int   flags[4];

    const int tid = threadIdx.x;
    const int s   = tid >> 6;       // wave index = sample-in-block
    const int l   = tid & 63;       // lane
    const int sample = blockIdx.x * 4 + s;

    // ---- stage weights into LDS (transpose + clip), coalesced global reads ----
    for (int idx = tid; idx < NH * NC; idx += 256) {
        const int r = idx >> 6, k = idx & 63;       // Wy* are (H=128, C=64) row-major
        Wy0s[k * 129 + r] = Wy0[idx];
        Wy1s[k * 129 + r] = Wy1[idx];
    }
    for (int idx = tid; idx < NH * NH; idx += 256) {
        const int r = idx >> 7, k = idx & 127;      // Wz1 is (128,128) row-major
        Wz1s[k * 129 + r] = fminf(fmaxf(Wz1[idx], 0.0f), 1e10f);
    }
    // per-lane constants (lane l owns component l of its sample, plus rows l, l+64)
    const float wy2  = Wy2[l];
    const float wz2a = fminf(fmaxf(Wz2[l],      0.0f), 1e10f);
    const float wz2b = fminf(fmaxf(Wz2[l + 64], 0.0f), 1e10f);
    const float b0a = by0[l], b0b = by0[l + 64];
    const float b1a = by1[l], b1b = by1[l + 64];
    const float b2  = by2[0];
    const float z   = xin[sample * NC + l];

    float x1     = z;        // start at z (much closer to x* than ones)
    float lam    = 1.0f;     // per-sample adaptive step
    float prev_n = 3.4e38f;  // previous residual norm
    bool frozen = false;
    __syncthreads();

    for (int it = 0; it < MAX_IT; ++it) {
        if (!frozen) xbuf[s][l] = x1;
        __syncthreads();

        float sig0a = 0.f, sig0b = 0.f, sig2 = 0.f;

        // ---- layer 0 forward: s0 = Wy0 x + by0 ----
        if (!frozen) {
            float a0 = b0a, a1 = b0b;
            #pragma unroll
            for (int k = 0; k < NC; ++k) {
                const float xk = xbuf[s][k];
                a0 = fmaf(Wy0s[k * 129 + l],      xk, a0);
                a1 = fmaf(Wy0s[k * 129 + l + 64], xk, a1);
            }
            sig0a = 1.0f / (1.0f + expf(-a0));
            sig0b = 1.0f / (1.0f + expf(-a1));
            h0buf[s][l]      = fmaxf(a0, 0.0f) + log1pf(expf(-fabsf(a0)));
            h0buf[s][l + 64] = fmaxf(a1, 0.0f) + log1pf(expf(-fabsf(a1)));
        }
        __syncthreads();

        // ---- layer 1 forward + scalar head + v1 ----
        if (!frozen) {
            float a0 = b1a, a1 = b1b;
            #pragma unroll 8
            for (int k = 0; k < NH; ++k) {
                const float hk = h0buf[s][k];
                a0 = fmaf(Wz1s[k * 129 + l],      hk, a0);
                a1 = fmaf(Wz1s[k * 129 + l + 64], hk, a1);
            }
            #pragma unroll
            for (int k = 0; k < NC; ++k) {
                const float xk = xbuf[s][k];
                a0 = fmaf(Wy1s[k * 129 + l],      xk, a0);
                a1 = fmaf(Wy1s[k * 129 + l + 64], xk, a1);
            }
            const float sig1a = 1.0f / (1.0f + expf(-a0));
            const float sig1b = 1.0f / (1.0f + expf(-a1));
            const float h1a = fmaxf(a0, 0.0f) + log1pf(expf(-fabsf(a0)));
            const float h1b = fmaxf(a1, 0.0f) + log1pf(expf(-fabsf(a1)));
            // s2 = Wz2.h1 + Wy2.x + by2  (wave butterfly reduction)
            float p = wz2a * h1a + wz2b * h1b + wy2 * x1;
            #pragma unroll
            for (int off = 32; off > 0; off >>= 1) p += __shfl_xor(p, off, 64);
            sig2 = 1.0f / (1.0f + expf(-(p + b2)));
            v1buf[s][l]      = sig2 * sig1a * wz2a;
            v1buf[s][l + 64] = sig2 * sig1b * wz2b;
        }
        __syncthreads();

        // ---- adjoint: v0 = sig0 * (Wz1^T v1) ----
        if (!frozen) {
            float t0 = 0.f, t1 = 0.f;
            #pragma unroll 8
            for (int j = 0; j < NH; ++j) {
                const float vj = v1buf[s][j];
                t0 = fmaf(Wz1s[l * 129 + j],        vj, t0);
                t1 = fmaf(Wz1s[(l + 64) * 129 + j], vj, t1);
            }
            v0buf[s][l]      = sig0a * t0;
            v0buf[s][l + 64] = sig0b * t1;
        }
        __syncthreads();

        // ---- g = x + sig2*Wy2^T + Wy1^T v1 + Wy0^T v0 ; adaptive update ----
        if (!frozen) {
            float g = fmaf(sig2, wy2, x1);
            #pragma unroll 8
            for (int j = 0; j < NH; ++j)
                g = fmaf(Wy1s[l * 129 + j], v1buf[s][j], g);
            #pragma unroll 8
            for (int j = 0; j < NH; ++j)
                g = fmaf(Wy0s[l * 129 + j], v0buf[s][j], g);
            const float resid = z - g;
            float n2 = resid * resid;
            #pragma unroll
            for (int off = 32; off > 0; off >>= 1) n2 += __shfl_xor(n2, off, 64);
            const float n = sqrtf(n2);
            if (n < TOLF) {
                frozen = true;             // converged: stop touching x1
            } else {
                // residual didn't decrease -> step too big for local curvature
                if (n > prev_n * 0.999f) lam *= 0.5f;
                // Halpern-style floor guarantees convergence even if the
                // halving is triggered spuriously by nonlinearity
                const float step = fmaxf(lam, 1.0f / (float)(it + 2));
                x1 = fmaf(step, resid, x1);
                prev_n = n;
            }
        }

        if (l == 0) flags[s] = frozen ? 1 : 0;
        __syncthreads();
        if ((flags[0] & flags[1] & flags[2] & flags[3]) != 0) break;
    }

    // output = x1 + CONVEX * z
    out[sample * NC + l] = x1 + z;
}

extern "C" void kernel_launch(void* const* d_in, const int* in_sizes, int n_in,
                              void* d_out, int out_size, void* d_ws, size_t ws_size,
                              hipStream_t stream) {
    const float* xin = (const float*)d_in[0];
    const float* Wy0 = (const float*)d_in[1];
    const float* by0 = (const float*)d_in[2];
    const float* Wy1 = (const float*)d_in[3];
    const float* by1 = (const float*)d_in[4];
    const float* Wz1 = (const float*)d_in[5];
    const float* Wy2 = (const float*)d_in[6];
    const float* by2 = (const float*)d_in[7];
    const float* Wz2 = (const float*)d_in[8];
    float* out = (float*)d_out;

    blnn_kernel<<<dim3(NB / 4), dim3(256), 0, stream>>>(
        xin, Wy0, by0, Wy1, by1, Wz1, Wy2, by2, Wz2, out);
}

// Round 3
// 107.630 us; speedup vs baseline: 3.2887x; 1.1760x over previous
//
#include <hip/hip_runtime.h>
#include <math.h>

#define NB 1024   // batch
#define NC 64     // input dim
#define NH 128    // hidden dim
#define MAX_IT 500
#define TOLF 1e-3f

typedef _Float16 h2 __attribute__((ext_vector_type(2)));

#if __has_builtin(__builtin_amdgcn_fdot2)
#define FDOT2(a, b, c) __builtin_amdgcn_fdot2((a), (b), (c), false)
#else
#define FDOT2(a, b, c) fmaf((float)(a).x, (float)(b).x, fmaf((float)(a).y, (float)(b).y, (c)))
#endif

#if __has_builtin(__builtin_amdgcn_wave_barrier)
#define WAVE_FENCE() __builtin_amdgcn_wave_barrier()
#else
#define WAVE_FENCE()
#endif

__device__ __forceinline__ unsigned pack_h2(float a, float b) {
    union { h2 h; unsigned u; } cv;
    cv.h.x = (_Float16)a; cv.h.y = (_Float16)b; return cv.u;
}
__device__ __forceinline__ h2 as_h2(unsigned u) {
    union { unsigned u; h2 h; } cv; cv.u = u; return cv.h;
}
__device__ __forceinline__ float rcp_fast(float x) {
#if __has_builtin(__builtin_amdgcn_rcpf)
    return __builtin_amdgcn_rcpf(x);
#else
    return 1.0f / x;
#endif
}
// sigmoid + softplus sharing one exp
__device__ __forceinline__ void sigsp(float a, float& sig, float& sp) {
    const float e = __expf(-fabsf(a));
    const float r = rcp_fast(1.0f + e);
    sig = (a >= 0.0f) ? r : e * r;
    sp  = fmaxf(a, 0.0f) + __logf(1.0f + e);
}

// One wave = one sample (lane c owns component c). All weights live in LDS as
// packed half2, in TWO layouts each so every matvec direction is a dot2 with
// conflict-free reads:
//   forward  P[pk][slot]: pairs along k, outputs interleaved (slot 2l -> row l,
//            2l+1 -> row l+64) so ONE b64 read feeds both output halves.
//   adjoint  T[pj][c]:    pairs along j (the reduced dim of W^T).
// No per-iteration barriers: every buffer is private to its wave; waves exit
// independently when their own sample converges.
__launch_bounds__(256, 1)
__global__ void blnn_kernel(const float* __restrict__ xin,
                            const float* __restrict__ Wy0,
                            const float* __restrict__ by0,
                            const float* __restrict__ Wy1,
                            const float* __restrict__ by1,
                            const float* __restrict__ Wz1,
                            const float* __restrict__ Wy2,
                            const float* __restrict__ by2,
                            const float* __restrict__ Wz2,
                            float* __restrict__ out)
{
    __shared__ __align__(16) unsigned P0i[32 * 128];  // Wy0 fwd: [pk][slot]
    __shared__ __align__(16) unsigned P1i[32 * 128];  // Wy1 fwd
    __shared__ __align__(16) unsigned PZi[64 * 128];  // Wz1 fwd (clipped)
    __shared__ __align__(16) unsigned TZi[64 * 128];  // Wz1 adj: [pj][slot 2l|2l+1 -> c=l|l+64]
    __shared__ __align__(16) unsigned T0i[64 * 64];   // Wy0 adj: [pj][c]
    __shared__ __align__(16) unsigned T1i[64 * 64];   // Wy1 adj
    __shared__ __align__(16) _Float16 xh [4][64];
    __shared__ __align__(16) _Float16 h0h[4][128];
    __shared__ __align__(16) _Float16 v1h[4][128];
    __shared__ __align__(16) _Float16 v0h[4][128];

    const int tid = threadIdx.x;
    const int s   = tid >> 6;
    const int l   = tid & 63;
    const int sample = blockIdx.x * 4 + s;

    // ---- stage weights: fp32 global -> packed fp16 LDS (both layouts) ----
    const float2* Wy0f2 = (const float2*)Wy0;   // [128][32] float2
    const float2* Wy1f2 = (const float2*)Wy1;
    const float2* Wz1f2 = (const float2*)Wz1;   // [128][64] float2
    for (int idx = tid; idx < 128 * 32; idx += 256) {        // P0/P1
        const int pk = idx & 31, r = idx >> 5;
        const int slot = ((r & 63) << 1) | (r >> 6);
        const float2 a = Wy0f2[idx], b = Wy1f2[idx];
        P0i[pk * 128 + slot] = pack_h2(a.x, a.y);
        P1i[pk * 128 + slot] = pack_h2(b.x, b.y);
    }
    for (int idx = tid; idx < 128 * 64; idx += 256) {        // PZ (clip >= 0)
        const int pk = idx & 63, r = idx >> 6;
        const int slot = ((r & 63) << 1) | (r >> 6);
        const float2 a = Wz1f2[idx];
        PZi[pk * 128 + slot] = pack_h2(fmaxf(a.x, 0.0f), fmaxf(a.y, 0.0f));
    }
    for (int idx = tid; idx < 64 * 128; idx += 256) {        // TZ (adjoint of clipped Wz1)
        const int c = idx & 127, pj = idx >> 7;
        const int slot = ((c & 63) << 1) | (c >> 6);
        TZi[pj * 128 + slot] = pack_h2(fmaxf(Wz1[(2 * pj) * 128 + c], 0.0f),
                                       fmaxf(Wz1[(2 * pj + 1) * 128 + c], 0.0f));
    }
    for (int idx = tid; idx < 64 * 64; idx += 256) {         // T0/T1
        const int c = idx & 63, pj = idx >> 6;
        T0i[pj * 64 + c] = pack_h2(Wy0[(2 * pj) * 64 + c], Wy0[(2 * pj + 1) * 64 + c]);
        T1i[pj * 64 + c] = pack_h2(Wy1[(2 * pj) * 64 + c], Wy1[(2 * pj + 1) * 64 + c]);
    }

    // per-lane constants
    const float wy2  = Wy2[l];
    const float wz2a = fmaxf(Wz2[l], 0.0f);
    const float wz2b = fmaxf(Wz2[l + 64], 0.0f);
    const float b0a = by0[l], b0b = by0[l + 64];
    const float b1a = by1[l], b1b = by1[l + 64];
    const float b2  = by2[0];
    const float z   = xin[sample * NC + l];

    __syncthreads();   // staging done — the ONLY block-wide barrier

    const h2* xh2  = (const h2*)&xh [s][0];
    const h2* h0h2 = (const h2*)&h0h[s][0];
    const h2* v1h2 = (const h2*)&v1h[s][0];
    const h2* v0h2 = (const h2*)&v0h[s][0];
    const uint2* W0 = (const uint2*)P0i;   // uint2 idx = pk*64 + l
    const uint2* W1 = (const uint2*)P1i;
    const uint2* WZ = (const uint2*)PZi;
    const uint2* AZ = (const uint2*)TZi;

    float x1 = z;            // start at z
    float lam = 1.0f, prev_n = 3.4e38f;

    for (int it = 0; it < MAX_IT; ++it) {
        xh[s][l] = (_Float16)x1;
        WAVE_FENCE();

        // ---- layer 0 forward: a = Wy0 x + by0 (rows l, l+64) ----
        float c00 = b0a, c01 = 0.f, c10 = b0b, c11 = 0.f;
        #pragma unroll
        for (int pk = 0; pk < 32; pk += 2) {
            const h2 xa = xh2[pk], xb = xh2[pk + 1];
            const uint2 wA = W0[pk * 64 + l];
            const uint2 wB = W0[(pk + 1) * 64 + l];
            c00 = FDOT2(as_h2(wA.x), xa, c00);
            c10 = FDOT2(as_h2(wA.y), xa, c10);
            c01 = FDOT2(as_h2(wB.x), xb, c01);
            c11 = FDOT2(as_h2(wB.y), xb, c11);
        }
        float sig0a, sp0a, sig0b, sp0b;
        sigsp(c00 + c01, sig0a, sp0a);
        sigsp(c10 + c11, sig0b, sp0b);
        h0h[s][l]      = (_Float16)sp0a;
        h0h[s][l + 64] = (_Float16)sp0b;
        WAVE_FENCE();

        // ---- layer 1 forward: a = Wz1+ h0 + Wy1 x + by1 ----
        c00 = b1a; c01 = 0.f; c10 = b1b; c11 = 0.f;
        #pragma unroll
        for (int pj = 0; pj < 64; pj += 2) {
            const h2 ha = h0h2[pj], hb = h0h2[pj + 1];
            const uint2 wA = WZ[pj * 64 + l];
            const uint2 wB = WZ[(pj + 1) * 64 + l];
            c00 = FDOT2(as_h2(wA.x), ha, c00);
            c10 = FDOT2(as_h2(wA.y), ha, c10);
            c01 = FDOT2(as_h2(wB.x), hb, c01);
            c11 = FDOT2(as_h2(wB.y), hb, c11);
        }
        #pragma unroll
        for (int pk = 0; pk < 32; pk += 2) {
            const h2 xa = xh2[pk], xb = xh2[pk + 1];
            const uint2 wA = W1[pk * 64 + l];
            const uint2 wB = W1[(pk + 1) * 64 + l];
            c00 = FDOT2(as_h2(wA.x), xa, c00);
            c10 = FDOT2(as_h2(wA.y), xa, c10);
            c01 = FDOT2(as_h2(wB.x), xb, c01);
            c11 = FDOT2(as_h2(wB.y), xb, c11);
        }
        float sig1a, h1a, sig1b, h1b;
        sigsp(c00 + c01, sig1a, h1a);
        sigsp(c10 + c11, sig1b, h1b);
        // scalar head: p = Wz2.h1 + Wy2.x + by2 (wave butterfly)
        float p = wz2a * h1a + wz2b * h1b + wy2 * x1;
        #pragma unroll
        for (int off = 32; off > 0; off >>= 1) p += __shfl_xor(p, off, 64);
        const float e2 = __expf(-fabsf(p + b2));
        const float r2 = rcp_fast(1.0f + e2);
        const float sig2 = ((p + b2) >= 0.0f) ? r2 : e2 * r2;
        v1h[s][l]      = (_Float16)(sig2 * sig1a * wz2a);
        v1h[s][l + 64] = (_Float16)(sig2 * sig1b * wz2b);
        WAVE_FENCE();

        // ---- adjoint: v0 = sig0 * (Wz1+^T v1)  (outputs c=l, l+64) ----
        float t00 = 0.f, t01 = 0.f, t10 = 0.f, t11 = 0.f;
        #pragma unroll
        for (int pj = 0; pj < 64; pj += 2) {
            const h2 va = v1h2[pj], vb = v1h2[pj + 1];
            const uint2 wA = AZ[pj * 64 + l];
            const uint2 wB = AZ[(pj + 1) * 64 + l];
            t00 = FDOT2(as_h2(wA.x), va, t00);
            t10 = FDOT2(as_h2(wA.y), va, t10);
            t01 = FDOT2(as_h2(wB.x), vb, t01);
            t11 = FDOT2(as_h2(wB.y), vb, t11);
        }
        v0h[s][l]      = (_Float16)(sig0a * (t00 + t01));
        v0h[s][l + 64] = (_Float16)(sig0b * (t10 + t11));
        WAVE_FENCE();

        // ---- g = x + sig2*Wy2^T + Wy1^T v1 + Wy0^T v0 (output c=l) ----
        float g0 = fmaf(sig2, wy2, x1), g1 = 0.f, g2 = 0.f, g3 = 0.f;
        #pragma unroll
        for (int pj = 0; pj < 64; pj += 2) {
            g0 = FDOT2(as_h2(T1i[pj * 64 + l]),       v1h2[pj],     g0);
            g1 = FDOT2(as_h2(T1i[(pj + 1) * 64 + l]), v1h2[pj + 1], g1);
        }
        #pragma unroll
        for (int pj = 0; pj < 64; pj += 2) {
            g2 = FDOT2(as_h2(T0i[pj * 64 + l]),       v0h2[pj],     g2);
            g3 = FDOT2(as_h2(T0i[(pj + 1) * 64 + l]), v0h2[pj + 1], g3);
        }
        const float g = (g0 + g1) + (g2 + g3);

        const float resid = z - g;
        float n2 = resid * resid;
        #pragma unroll
        for (int off = 32; off > 0; off >>= 1) n2 += __shfl_xor(n2, off, 64);
        const float n = sqrtf(n2);
        if (n < TOLF) break;                       // this wave is done
        if (n > prev_n * 0.999f) lam *= 0.5f;      // adaptive Richardson
        const float step = fmaxf(lam, 1.0f / (float)(it + 2));
        x1 = fmaf(step, resid, x1);
        prev_n = n;
    }

    out[sample * NC + l] = x1 + z;   // + CONVEX * z
}

extern "C" void kernel_launch(void* const* d_in, const int* in_sizes, int n_in,
                              void* d_out, int out_size, void* d_ws, size_t ws_size,
                              hipStream_t stream) {
    const float* xin = (const float*)d_in[0];
    const float* Wy0 = (const float*)d_in[1];
    const float* by0 = (const float*)d_in[2];
    const float* Wy1 = (const float*)d_in[3];
    const float* by1 = (const float*)d_in[4];
    const float* Wz1 = (const float*)d_in[5];
    const float* Wy2 = (const float*)d_in[6];
    const float* by2 = (const float*)d_in[7];
    const float* Wz2 = (const float*)d_in[8];
    float* out = (float*)d_out;

    blnn_kernel<<<dim3(NB / 4), dim3(256), 0, stream>>>(
        xin, Wy0, by0, Wy1, by1, Wz1, Wy2, by2, Wz2, out);
}

// Round 4
// 104.465 us; speedup vs baseline: 3.3883x; 1.0303x over previous
//
#include <hip/hip_runtime.h>
#include <math.h>

#define NB 1024   // batch
#define NC 64     // input dim
#define NH 128    // hidden dim
#define MAX_IT 500
#define TOLF 1e-3f

typedef _Float16 h2 __attribute__((ext_vector_type(2)));

#if __has_builtin(__builtin_amdgcn_fdot2)
#define FDOT2(a, b, c) __builtin_amdgcn_fdot2((a), (b), (c), false)
#else
#define FDOT2(a, b, c) fmaf((float)(a).x, (float)(b).x, fmaf((float)(a).y, (float)(b).y, (c)))
#endif

#if __has_builtin(__builtin_amdgcn_wave_barrier)
#define WAVE_FENCE() __builtin_amdgcn_wave_barrier()
#else
#define WAVE_FENCE()
#endif

__device__ __forceinline__ unsigned pack_h2(float a, float b) {
    union { h2 h; unsigned u; } cv;
    cv.h.x = (_Float16)a; cv.h.y = (_Float16)b; return cv.u;
}
__device__ __forceinline__ h2 as_h2(unsigned u) {
    union { unsigned u; h2 h; } cv; cv.u = u; return cv.h;
}
__device__ __forceinline__ float rcp_fast(float x) {
#if __has_builtin(__builtin_amdgcn_rcpf)
    return __builtin_amdgcn_rcpf(x);
#else
    return 1.0f / x;
#endif
}
// sigmoid + softplus sharing one exp
__device__ __forceinline__ void sigsp(float a, float& sig, float& sp) {
    const float e = __expf(-fabsf(a));
    const float r = rcp_fast(1.0f + e);
    sig = (a >= 0.0f) ? r : e * r;
    sp  = fmaxf(a, 0.0f) + __logf(1.0f + e);
}

// One wave = one sample (lane c owns component c). Weights in LDS as packed
// half2 in two layouts (forward / adjoint), conflict-free in both directions.
// This structure sits at the LDS unique-bytes roofline (~128 KB/wave/iter), so
// round 4's lever is ITERATION COUNT: Anderson(m=1)-accelerated Richardson
// (secant step along the dominant error mode) with clamped gamma + residual
// safeguards; typically 2-3x fewer iterations than plain adaptive Richardson.
__launch_bounds__(256, 1)
__global__ void blnn_kernel(const float* __restrict__ xin,
                            const float* __restrict__ Wy0,
                            const float* __restrict__ by0,
                            const float* __restrict__ Wy1,
                            const float* __restrict__ by1,
                            const float* __restrict__ Wz1,
                            const float* __restrict__ Wy2,
                            const float* __restrict__ by2,
                            const float* __restrict__ Wz2,
                            float* __restrict__ out)
{
    __shared__ __align__(16) unsigned P0i[32 * 128];  // Wy0 fwd: [pk][slot]
    __shared__ __align__(16) unsigned P1i[32 * 128];  // Wy1 fwd
    __shared__ __align__(16) unsigned PZi[64 * 128];  // Wz1 fwd (clipped)
    __shared__ __align__(16) unsigned TZi[64 * 128];  // Wz1 adj
    __shared__ __align__(16) unsigned T0i[64 * 64];   // Wy0 adj: [pj][c]
    __shared__ __align__(16) unsigned T1i[64 * 64];   // Wy1 adj
    __shared__ __align__(16) _Float16 xh [4][64];
    __shared__ __align__(16) _Float16 h0h[4][128];
    __shared__ __align__(16) _Float16 v1h[4][128];
    __shared__ __align__(16) _Float16 v0h[4][128];

    const int tid = threadIdx.x;
    const int s   = tid >> 6;
    const int l   = tid & 63;
    const int sample = blockIdx.x * 4 + s;

    // ---- stage weights: fp32 global -> packed fp16 LDS (both layouts) ----
    const float2* Wy0f2 = (const float2*)Wy0;   // [128][32] float2
    const float2* Wy1f2 = (const float2*)Wy1;
    const float2* Wz1f2 = (const float2*)Wz1;   // [128][64] float2
    for (int idx = tid; idx < 128 * 32; idx += 256) {        // P0/P1
        const int pk = idx & 31, r = idx >> 5;
        const int slot = ((r & 63) << 1) | (r >> 6);
        const float2 a = Wy0f2[idx], b = Wy1f2[idx];
        P0i[pk * 128 + slot] = pack_h2(a.x, a.y);
        P1i[pk * 128 + slot] = pack_h2(b.x, b.y);
    }
    for (int idx = tid; idx < 128 * 64; idx += 256) {        // PZ (clip >= 0)
        const int pk = idx & 63, r = idx >> 6;
        const int slot = ((r & 63) << 1) | (r >> 6);
        const float2 a = Wz1f2[idx];
        PZi[pk * 128 + slot] = pack_h2(fmaxf(a.x, 0.0f), fmaxf(a.y, 0.0f));
    }
    for (int idx = tid; idx < 64 * 128; idx += 256) {        // TZ (adjoint of clipped Wz1)
        const int c = idx & 127, pj = idx >> 7;
        const int slot = ((c & 63) << 1) | (c >> 6);
        TZi[pj * 128 + slot] = pack_h2(fmaxf(Wz1[(2 * pj) * 128 + c], 0.0f),
                                       fmaxf(Wz1[(2 * pj + 1) * 128 + c], 0.0f));
    }
    for (int idx = tid; idx < 64 * 64; idx += 256) {         // T0/T1
        const int c = idx & 63, pj = idx >> 6;
        T0i[pj * 64 + c] = pack_h2(Wy0[(2 * pj) * 64 + c], Wy0[(2 * pj + 1) * 64 + c]);
        T1i[pj * 64 + c] = pack_h2(Wy1[(2 * pj) * 64 + c], Wy1[(2 * pj + 1) * 64 + c]);
    }

    // per-lane constants
    const float wy2  = Wy2[l];
    const float wz2a = fmaxf(Wz2[l], 0.0f);
    const float wz2b = fmaxf(Wz2[l + 64], 0.0f);
    const float b0a = by0[l], b0b = by0[l + 64];
    const float b1a = by1[l], b1b = by1[l + 64];
    const float b2  = by2[0];
    const float z   = xin[sample * NC + l];

    __syncthreads();   // staging done — the ONLY block-wide barrier

    const h2* xh2  = (const h2*)&xh [s][0];
    const h2* h0h2 = (const h2*)&h0h[s][0];
    const h2* v1h2 = (const h2*)&v1h[s][0];
    const h2* v0h2 = (const h2*)&v0h[s][0];
    const uint2* W0 = (const uint2*)P0i;   // uint2 idx = pk*64 + l
    const uint2* W1 = (const uint2*)P1i;
    const uint2* WZ = (const uint2*)PZi;
    const uint2* AZ = (const uint2*)TZi;

    float x1 = z;            // start at z
    float lam = 1.0f, prev_n = 3.4e38f;
    float x_prev = z, r_prev = 0.0f;   // Anderson(1) history

    for (int it = 0; it < MAX_IT; ++it) {
        xh[s][l] = (_Float16)x1;
        WAVE_FENCE();

        // ---- layer 0 forward: a = Wy0 x + by0 (rows l, l+64) ----
        float c00 = b0a, c01 = 0.f, c10 = b0b, c11 = 0.f;
        #pragma unroll
        for (int pk = 0; pk < 32; pk += 2) {
            const h2 xa = xh2[pk], xb = xh2[pk + 1];
            const uint2 wA = W0[pk * 64 + l];
            const uint2 wB = W0[(pk + 1) * 64 + l];
            c00 = FDOT2(as_h2(wA.x), xa, c00);
            c10 = FDOT2(as_h2(wA.y), xa, c10);
            c01 = FDOT2(as_h2(wB.x), xb, c01);
            c11 = FDOT2(as_h2(wB.y), xb, c11);
        }
        float sig0a, sp0a, sig0b, sp0b;
        sigsp(c00 + c01, sig0a, sp0a);
        sigsp(c10 + c11, sig0b, sp0b);
        h0h[s][l]      = (_Float16)sp0a;
        h0h[s][l + 64] = (_Float16)sp0b;
        WAVE_FENCE();

        // ---- layer 1 forward: a = Wz1+ h0 + Wy1 x + by1 ----
        c00 = b1a; c01 = 0.f; c10 = b1b; c11 = 0.f;
        #pragma unroll
        for (int pj = 0; pj < 64; pj += 2) {
            const h2 ha = h0h2[pj], hb = h0h2[pj + 1];
            const uint2 wA = WZ[pj * 64 + l];
            const uint2 wB = WZ[(pj + 1) * 64 + l];
            c00 = FDOT2(as_h2(wA.x), ha, c00);
            c10 = FDOT2(as_h2(wA.y), ha, c10);
            c01 = FDOT2(as_h2(wB.x), hb, c01);
            c11 = FDOT2(as_h2(wB.y), hb, c11);
        }
        #pragma unroll
        for (int pk = 0; pk < 32; pk += 2) {
            const h2 xa = xh2[pk], xb = xh2[pk + 1];
            const uint2 wA = W1[pk * 64 + l];
            const uint2 wB = W1[(pk + 1) * 64 + l];
            c00 = FDOT2(as_h2(wA.x), xa, c00);
            c10 = FDOT2(as_h2(wA.y), xa, c10);
            c01 = FDOT2(as_h2(wB.x), xb, c01);
            c11 = FDOT2(as_h2(wB.y), xb, c11);
        }
        float sig1a, h1a, sig1b, h1b;
        sigsp(c00 + c01, sig1a, h1a);
        sigsp(c10 + c11, sig1b, h1b);
        // scalar head: p = Wz2.h1 + Wy2.x + by2 (wave butterfly)
        float p = wz2a * h1a + wz2b * h1b + wy2 * x1;
        #pragma unroll
        for (int off = 32; off > 0; off >>= 1) p += __shfl_xor(p, off, 64);
        const float e2 = __expf(-fabsf(p + b2));
        const float r2 = rcp_fast(1.0f + e2);
        const float sig2 = ((p + b2) >= 0.0f) ? r2 : e2 * r2;
        v1h[s][l]      = (_Float16)(sig2 * sig1a * wz2a);
        v1h[s][l + 64] = (_Float16)(sig2 * sig1b * wz2b);
        WAVE_FENCE();

        // ---- adjoint: v0 = sig0 * (Wz1+^T v1)  (outputs c=l, l+64) ----
        float t00 = 0.f, t01 = 0.f, t10 = 0.f, t11 = 0.f;
        #pragma unroll
        for (int pj = 0; pj < 64; pj += 2) {
            const h2 va = v1h2[pj], vb = v1h2[pj + 1];
            const uint2 wA = AZ[pj * 64 + l];
            const uint2 wB = AZ[(pj + 1) * 64 + l];
            t00 = FDOT2(as_h2(wA.x), va, t00);
            t10 = FDOT2(as_h2(wA.y), va, t10);
            t01 = FDOT2(as_h2(wB.x), vb, t01);
            t11 = FDOT2(as_h2(wB.y), vb, t11);
        }
        v0h[s][l]      = (_Float16)(sig0a * (t00 + t01));
        v0h[s][l + 64] = (_Float16)(sig0b * (t10 + t11));
        WAVE_FENCE();

        // ---- g = x + sig2*Wy2^T + Wy1^T v1 + Wy0^T v0 (output c=l) ----
        float g0 = fmaf(sig2, wy2, x1), g1 = 0.f, g2 = 0.f, g3 = 0.f;
        #pragma unroll
        for (int pj = 0; pj < 64; pj += 2) {
            g0 = FDOT2(as_h2(T1i[pj * 64 + l]),       v1h2[pj],     g0);
            g1 = FDOT2(as_h2(T1i[(pj + 1) * 64 + l]), v1h2[pj + 1], g1);
        }
        #pragma unroll
        for (int pj = 0; pj < 64; pj += 2) {
            g2 = FDOT2(as_h2(T0i[pj * 64 + l]),       v0h2[pj],     g2);
            g3 = FDOT2(as_h2(T0i[(pj + 1) * 64 + l]), v0h2[pj + 1], g3);
        }
        const float g = (g0 + g1) + (g2 + g3);

        // ---- Anderson(1)-accelerated Richardson update ----
        const float resid = z - g;
        float n2 = resid * resid;
        #pragma unroll
        for (int off = 32; off > 0; off >>= 1) n2 += __shfl_xor(n2, off, 64);
        const float n = sqrtf(n2);
        if (n < TOLF) break;                       // this wave is done

        const float dr = resid - r_prev;           // residual difference
        float d2 = dr * dr, rd = resid * dr;
        #pragma unroll
        for (int off = 32; off > 0; off >>= 1) {
            d2 += __shfl_xor(d2, off, 64);
            rd += __shfl_xor(rd, off, 64);
        }
        float gamma = 0.0f;
        if (it > 0 && d2 > 1e-16f) gamma = rd / d2;
        gamma = fminf(fmaxf(gamma, -1.5f), 1.5f);  // secant safeguard

        if (n > 2.0f * prev_n) {                   // diverging: damp, drop AA
            lam *= 0.5f;
            gamma = 0.0f;
        } else if (n < prev_n) {                   // recovering: regrow step
            lam = fminf(lam * 1.25f, 1.0f);
        }
        const float step = fmaxf(lam, 1.0f / (float)(it + 2));
        const float xn = x1 + step * resid - gamma * ((x1 - x_prev) + step * dr);
        x_prev = x1; r_prev = resid;
        x1 = xn;
        prev_n = n;
    }

    out[sample * NC + l] = x1 + z;   // + CONVEX * z
}

extern "C" void kernel_launch(void* const* d_in, const int* in_sizes, int n_in,
                              void* d_out, int out_size, void* d_ws, size_t ws_size,
                              hipStream_t stream) {
    const float* xin = (const float*)d_in[0];
    const float* Wy0 = (const float*)d_in[1];
    const float* by0 = (const float*)d_in[2];
    const float* Wy1 = (const float*)d_in[3];
    const float* by1 = (const float*)d_in[4];
    const float* Wz1 = (const float*)d_in[5];
    const float* Wy2 = (const float*)d_in[6];
    const float* by2 = (const float*)d_in[7];
    const float* Wz2 = (const float*)d_in[8];
    float* out = (float*)d_out;

    blnn_kernel<<<dim3(NB / 4), dim3(256), 0, stream>>>(
        xin, Wy0, by0, Wy1, by1, Wz1, Wy2, by2, Wz2, out);
}